// Round 4
// baseline (235.913 us; speedup 1.0000x reference)
//
#include <hip/hip_runtime.h>
#include <math.h>

// IdealScore: B=16, N=10000, D=3072, fp32.
//   arg[b][n] = (at/bt2)*dot(x_b, img_n) - ((1-sval)/(2*sval))*||img_n||^2
//   (x_sq dropped: softmax shift-invariant per row)
//   w = softmax_n(arg); mix = w @ imgs; out = (at*mix - x)/bt2
//
// Near-one-hot softmax (arg std ~88): rows with arg < m-40 have weight
// <= 4e-18 -> sparse gather pass 2 over the ~1-5 surviving rows per b.
//
// R4: k1 = pure-TLP GEMM pass. No LDS, no barriers (R3 showed barrier
// drains + VGPR=132 regressed). Grid (625 n-groups x 4 d-quarters),
// 4 waves/block; each wave: 4 rows x 768 floats, 64 accumulators,
// reduce-scatter epilogue (6-step exchange, result lands distributed),
// c1/c2 folded so pd[b][n][4] is the only intermediate (2.56 MB).
#define BB 16
#define NN 10000
#define DD 3072
#define SEL_CUT 40.0f

// 6-step butterfly reduce-scatter over 64 lanes for 64 accumulators.
// After all steps lane L holds the full sum of acc[L].
#define RSTEP(mm, cc)                                              \
  {                                                                \
    const bool up = (lane & (mm)) != 0;                            \
    _Pragma("unroll")                                              \
    for (int k = 0; k < (cc); ++k) {                               \
      float lo = acc[k], hi = acc[k + (cc)];                       \
      float send = up ? lo : hi;                                   \
      float recv = __shfl_xor(send, (mm), 64);                     \
      acc[k] = (up ? hi : lo) + recv;                              \
    }                                                              \
  }

// ---- K1: pd[b][n][q] = c1*dot_q(x_b, img_n) - c2*isq_q(n) ----
__global__ __launch_bounds__(256, 3) void k1_partial(
    const float* __restrict__ x, const float* __restrict__ images,
    const float* __restrict__ svalp, float* __restrict__ pd)
{
  const int t = threadIdx.x;
  const int lane = t & 63;
  const int wave = t >> 6;
  const int n0 = blockIdx.x * 16 + wave * 4;   // 625*16 = 10000 exactly
  const int q = blockIdx.y;                    // d-quarter 0..3
  const int d0 = q * 768;

  float acc[64];                               // j = b*4 + r
  float isq[4];
#pragma unroll
  for (int j = 0; j < 64; ++j) acc[j] = 0.f;
#pragma unroll
  for (int r = 0; r < 4; ++r) isq[r] = 0.f;

#pragma unroll 1
  for (int c = 0; c < 3; ++c) {
    const int dg = d0 + c * 256 + (lane << 2);
    float4 im[4];
#pragma unroll
    for (int r = 0; r < 4; ++r)
      im[r] = *(const float4*)&images[(size_t)(n0 + r) * DD + dg];
#pragma unroll
    for (int r = 0; r < 4; ++r)
      isq[r] += im[r].x * im[r].x + im[r].y * im[r].y +
                im[r].z * im[r].z + im[r].w * im[r].w;
#pragma unroll
    for (int b = 0; b < BB; ++b) {
      float4 xv = *(const float4*)&x[b * DD + dg];   // L1/L2-hot
#pragma unroll
      for (int r = 0; r < 4; ++r)
        acc[b * 4 + r] += im[r].x * xv.x + im[r].y * xv.y +
                          im[r].z * xv.z + im[r].w * xv.w;
    }
  }

  RSTEP(32, 32)
  RSTEP(16, 16)
  RSTEP(8, 8)
  RSTEP(4, 4)
  RSTEP(2, 2)
  RSTEP(1, 1)
  // acc[0] on lane L = full dot for b = L>>2, r = L&3

#pragma unroll
  for (int r = 0; r < 4; ++r) {
    float v = isq[r];
#pragma unroll
    for (int m = 32; m >= 1; m >>= 1) v += __shfl_xor(v, m, 64);
    isq[r] = v;                                // all lanes: full isq
  }

  const float sval = *svalp;
  const float at = sqrtf(1.f - sval);
  const float c1 = at / sval;                    // at / bt2
  const float c2 = (1.f - sval) / (2.f * sval);  // at^2 / (2*bt2)

  const int b = lane >> 2;
  const int r = lane & 3;
  float myisq = isq[0];                          // cndmask chain, no scratch
  if (r == 1) myisq = isq[1];
  if (r == 2) myisq = isq[2];
  if (r == 3) myisq = isq[3];

  pd[(size_t)b * NN * 4 + (size_t)(n0 + r) * 4 + q] = c1 * acc[0] - c2 * myisq;
}

// ---- K2: args from pd (one float4 per (b,n)) -> stats + select ----
// 16 blocks x 1024 thr. Thread t owns n = t, t+1024, ... (<=10 values);
// single global pass, reductions from registers.
__global__ __launch_bounds__(1024) void k2_select(
    const float* __restrict__ pd, int* __restrict__ cnt,
    int* __restrict__ idx, float* __restrict__ wv)
{
  __shared__ float red[16];
  __shared__ float mshared, lshared;
  const int b = blockIdx.x;
  const int t = threadIdx.x;
  const int lane = t & 63, wave = t >> 6;
  if (t == 0) cnt[b] = 0;                    // ws is poisoned 0xAA

  float a[10];
#pragma unroll
  for (int i = 0; i < 10; ++i) {
    int n = t + (i << 10);
    if (n < NN) {
      float4 p = *(const float4*)&pd[(size_t)b * NN * 4 + (size_t)n * 4];
      a[i] = (p.x + p.y) + (p.z + p.w);
    } else {
      a[i] = -INFINITY;
    }
  }

  float mx = -INFINITY;
#pragma unroll
  for (int i = 0; i < 10; ++i) mx = fmaxf(mx, a[i]);
#pragma unroll
  for (int m = 32; m >= 1; m >>= 1) mx = fmaxf(mx, __shfl_xor(mx, m, 64));
  if (lane == 0) red[wave] = mx;
  __syncthreads();
  if (wave == 0) {
    float v = (lane < 16) ? red[lane] : -INFINITY;
#pragma unroll
    for (int m = 8; m >= 1; m >>= 1) v = fmaxf(v, __shfl_xor(v, m, 64));
    if (lane == 0) mshared = v;
  }
  __syncthreads();
  mx = mshared;

  float s = 0.f;
#pragma unroll
  for (int i = 0; i < 10; ++i) s += __expf(a[i] - mx);  // exp(-inf)=0
#pragma unroll
  for (int m = 32; m >= 1; m >>= 1) s += __shfl_xor(s, m, 64);
  if (lane == 0) red[wave] = s;
  __syncthreads();
  if (wave == 0) {
    float v = (lane < 16) ? red[lane] : 0.f;
#pragma unroll
    for (int m = 8; m >= 1; m >>= 1) v += __shfl_xor(v, m, 64);
    if (lane == 0) lshared = v;
  }
  __syncthreads();
  const float invl = 1.f / lshared;

#pragma unroll
  for (int i = 0; i < 10; ++i) {
    if (a[i] > mx - SEL_CUT) {               // ~1-5 hits per row
      int k = atomicAdd(&cnt[b], 1);
      idx[b * NN + k] = t + (i << 10);
      wv[b * NN + k] = __expf(a[i] - mx) * invl;
    }
  }
}

// ---- K3: sparse mix + fused final affine -> out ----
__global__ __launch_bounds__(256) void k3_sparse(
    const float* __restrict__ images, const float* __restrict__ x,
    const float* __restrict__ svalp, const int* __restrict__ cnt,
    const int* __restrict__ idx, const float* __restrict__ wv,
    float* __restrict__ out)
{
  const int b = blockIdx.y;
  const int d0 = blockIdx.x * 1024 + (threadIdx.x << 2);
  const int c = cnt[b];

  float4 acc = make_float4(0.f, 0.f, 0.f, 0.f);
  for (int j = 0; j < c; ++j) {
    int n = idx[b * NN + j];
    float w = wv[b * NN + j];
    float4 im = *(const float4*)&images[(size_t)n * DD + d0];
    acc.x += w * im.x; acc.y += w * im.y;
    acc.z += w * im.z; acc.w += w * im.w;
  }

  const float sval = *svalp;
  const float at = sqrtf(1.f - sval);
  const float inv_bt2 = 1.f / sval;
  float4 xv = *(const float4*)&x[b * DD + d0];
  float4 o;
  o.x = (at * acc.x - xv.x) * inv_bt2;
  o.y = (at * acc.y - xv.y) * inv_bt2;
  o.z = (at * acc.z - xv.z) * inv_bt2;
  o.w = (at * acc.w - xv.w) * inv_bt2;
  *(float4*)&out[b * DD + d0] = o;
}

extern "C" void kernel_launch(void* const* d_in, const int* in_sizes, int n_in,
                              void* d_out, int out_size, void* d_ws, size_t ws_size,
                              hipStream_t stream) {
  const float* x      = (const float*)d_in[0];
  const float* images = (const float*)d_in[1];
  const float* sval   = (const float*)d_in[2];
  float* out = (float*)d_out;
  float* ws  = (float*)d_ws;

  // ws layout (floats): pd[16*10000*4] | cnt[16]i | pad[16] |
  //                     idx[16*10000]i | wv[16*10000]  -> 3.84 MB total
  float* pd  = ws;
  int*   cnt = (int*)(ws + 640000);
  int*   idx = (int*)(ws + 640032);
  float* wv  = ws + 800032;

  hipLaunchKernelGGL(k1_partial, dim3(625, 4), dim3(256), 0, stream,
                     x, images, sval, pd);
  hipLaunchKernelGGL(k2_select, dim3(16), dim3(1024), 0, stream,
                     pd, cnt, idx, wv);
  hipLaunchKernelGGL(k3_sparse, dim3(3, 16), dim3(256), 0, stream,
                     images, x, sval, cnt, idx, wv, out);
}

// Round 6
// 211.321 us; speedup vs baseline: 1.1164x; 1.1164x over previous
//
#include <hip/hip_runtime.h>
#include <math.h>

// IdealScore: B=16, N=10000, D=3072, fp32.
//   arg[b][n] = (at/bt2)*dot(x_b, img_n) - ((1-sval)/(2*sval))*||img_n||^2
//   (x_sq dropped: softmax shift-invariant); w = softmax_n(arg);
//   out = (at*(w@imgs) - x)/bt2.  Near-one-hot softmax -> sparse pass 2.
//
// R6 = R5 structure with the reduce-scatter completed (R5 bug: masks
// {32,16,8,4} scatter 16 accumulators but bits {2,1} were never summed ->
// partial dots). Plus pd relaid as [q][b][n] so each wave writes full
// 64B lines per b (R5's [b][n][q] scattered 32 dwords/group across
// q-shared cachelines).
#define BB 16
#define NN 10000
#define DD 3072
#define QQ 12            // d-chunks of 256 floats
#define SEL_CUT 40.0f
#define CAP 1024         // selection capacity per batch row

// reduce-scatter step on float2 accumulators accp[]
#define RSTEP2(mm, cc)                                                  \
  {                                                                     \
    const bool up = (lane & (mm)) != 0;                                 \
    _Pragma("unroll")                                                   \
    for (int k = 0; k < (cc); ++k) {                                    \
      float2 lo = accp[k], hi = accp[k + (cc)];                         \
      float sx = up ? lo.x : hi.x, sy = up ? lo.y : hi.y;               \
      float rx = __shfl_xor(sx, (mm), 64);                              \
      float ry = __shfl_xor(sy, (mm), 64);                              \
      accp[k].x = (up ? hi.x : lo.x) + rx;                              \
      accp[k].y = (up ? hi.y : lo.y) + ry;                              \
    }                                                                   \
  }

// ---- K1: pd[q][b][n] = c1*dot_q(x_b, img_n) - c2*isq_q(n) ----
// grid (157 n-groups, 12 d-chunks) x 256 thr. Wave handles 16 rows
// (8 groups of 2) x one 256-float d-chunk x all 16 b.
// Persistent regs: x slice (64 VGPR, loaded once). Streaming: 2 image
// rows/group -> 32 accumulator floats, reduce-scattered immediately.
// No LDS, no barriers (R3: barrier drains regress a latency-bound loop).
__global__ __launch_bounds__(256) void k1_partial(
    const float* __restrict__ x, const float* __restrict__ images,
    const float* __restrict__ svalp, float* __restrict__ pd)
{
  const int t = threadIdx.x;
  const int lane = t & 63;
  const int wave = t >> 6;
  const int q = blockIdx.y;
  const int dg = q * 256 + (lane << 2);
  const int n0 = (blockIdx.x * 4 + wave) * 16;   // 628 waves cover 10048 rows

  // persistent x slice: 16 rows x 4 floats = 64 VGPR, loaded ONCE
  float4 xr[BB];
#pragma unroll
  for (int b = 0; b < BB; ++b)
    xr[b] = *(const float4*)&x[b * DD + dg];

  const float sval = *svalp;
  const float at = sqrtf(1.f - sval);
  const float k1c = at / sval;                    // at / bt2
  const float k2c = (1.f - sval) / (2.f * sval);  // at^2 / (2*bt2)

  int n = n0;
  float4 A0 = *(const float4*)&images[(size_t)(n < NN ? n : NN - 1) * DD + dg];
  float4 A1 = *(const float4*)&images[(size_t)(n + 1 < NN ? n + 1 : NN - 1) * DD + dg];

#pragma unroll 1
  for (int g = 0; g < 8; ++g) {
    // unpack current pair into component-pairs (frees A for prefetch)
    float2 p0 = make_float2(A0.x, A1.x);
    float2 p1 = make_float2(A0.y, A1.y);
    float2 p2 = make_float2(A0.z, A1.z);
    float2 p3 = make_float2(A0.w, A1.w);

    const int n2 = n + 2;
    if (g != 7) {                                // uniform branch
      A0 = *(const float4*)&images[(size_t)(n2 < NN ? n2 : NN - 1) * DD + dg];
      A1 = *(const float4*)&images[(size_t)(n2 + 1 < NN ? n2 + 1 : NN - 1) * DD + dg];
    }

    float2 isqp;
    isqp.x = p0.x * p0.x + p1.x * p1.x + p2.x * p2.x + p3.x * p3.x;
    isqp.y = p0.y * p0.y + p1.y * p1.y + p2.y * p2.y + p3.y * p3.y;

    float2 accp[BB];
#pragma unroll
    for (int b = 0; b < BB; ++b) {
      accp[b].x = p0.x * xr[b].x + p1.x * xr[b].y +
                  p2.x * xr[b].z + p3.x * xr[b].w;
      accp[b].y = p0.y * xr[b].x + p1.y * xr[b].y +
                  p2.y * xr[b].z + p3.y * xr[b].w;
    }

    // reduce-scatter over lane bits {32,16,8,4}: lane group -> b index
    RSTEP2(32, 8)
    RSTEP2(16, 4)
    RSTEP2(8, 2)
    RSTEP2(4, 1)
    // R5 BUG FIX: bits {2,1} still unreduced -> plain butterfly completes
    accp[0].x += __shfl_xor(accp[0].x, 2, 64);
    accp[0].y += __shfl_xor(accp[0].y, 2, 64);
    accp[0].x += __shfl_xor(accp[0].x, 1, 64);
    accp[0].y += __shfl_xor(accp[0].y, 1, 64);
    // now all 4 lanes of each group hold the FULL dot for b=(lane>>2)&15

#pragma unroll
    for (int m = 32; m >= 1; m >>= 1) {
      isqp.x += __shfl_xor(isqp.x, m, 64);
      isqp.y += __shfl_xor(isqp.y, m, 64);
    }

    const int r = lane & 1;
    const int bb = (lane >> 2) & 15;
    const int nn = n + r;
    float dotv = r ? accp[0].y : accp[0].x;
    float isv  = r ? isqp.y    : isqp.x;
    if ((lane & 2) == 0 && nn < NN)
      pd[((size_t)q * BB + bb) * NN + nn] = k1c * dotv - k2c * isv;

    n = n2;
  }
}

// ---- K2: args = sum_q pd[q][b][n] -> stats + select ----
// 16 blocks x 1024 thr; thread t owns n = t, t+1024, ... (<=10 values).
// Each of the 12 q-loads is coalesced across n.
__global__ __launch_bounds__(1024) void k2_select(
    const float* __restrict__ pd, int* __restrict__ cnt,
    int* __restrict__ idx, float* __restrict__ wv)
{
  __shared__ float red[16];
  __shared__ float mshared, lshared;
  const int b = blockIdx.x;
  const int t = threadIdx.x;
  const int lane = t & 63, wave = t >> 6;
  if (t == 0) cnt[b] = 0;                    // ws is poisoned 0xAA

  float a[10];
#pragma unroll
  for (int i = 0; i < 10; ++i) {
    int n = t + (i << 10);
    if (n < NN) {
      float s = 0.f;
#pragma unroll
      for (int qq = 0; qq < QQ; ++qq)
        s += pd[((size_t)qq * BB + b) * NN + n];
      a[i] = s;
    } else {
      a[i] = -INFINITY;
    }
  }

  float mx = -INFINITY;
#pragma unroll
  for (int i = 0; i < 10; ++i) mx = fmaxf(mx, a[i]);
#pragma unroll
  for (int m = 32; m >= 1; m >>= 1) mx = fmaxf(mx, __shfl_xor(mx, m, 64));
  if (lane == 0) red[wave] = mx;
  __syncthreads();
  if (wave == 0) {
    float v = (lane < 16) ? red[lane] : -INFINITY;
#pragma unroll
    for (int m = 8; m >= 1; m >>= 1) v = fmaxf(v, __shfl_xor(v, m, 64));
    if (lane == 0) mshared = v;
  }
  __syncthreads();
  mx = mshared;

  float s = 0.f;
#pragma unroll
  for (int i = 0; i < 10; ++i) s += __expf(a[i] - mx);  // exp(-inf)=0
#pragma unroll
  for (int m = 32; m >= 1; m >>= 1) s += __shfl_xor(s, m, 64);
  if (lane == 0) red[wave] = s;
  __syncthreads();
  if (wave == 0) {
    float v = (lane < 16) ? red[lane] : 0.f;
#pragma unroll
    for (int m = 8; m >= 1; m >>= 1) v += __shfl_xor(v, m, 64);
    if (lane == 0) lshared = v;
  }
  __syncthreads();
  const float invl = 1.f / lshared;

#pragma unroll
  for (int i = 0; i < 10; ++i) {
    if (a[i] > mx - SEL_CUT) {               // ~1-5 hits per row
      int k = atomicAdd(&cnt[b], 1);
      if (k < CAP) {
        idx[b * CAP + k] = t + (i << 10);
        wv[b * CAP + k] = __expf(a[i] - mx) * invl;
      }
    }
  }
}

// ---- K3: sparse mix + fused final affine -> out ----
__global__ __launch_bounds__(256) void k3_sparse(
    const float* __restrict__ images, const float* __restrict__ x,
    const float* __restrict__ svalp, const int* __restrict__ cnt,
    const int* __restrict__ idx, const float* __restrict__ wv,
    float* __restrict__ out)
{
  const int b = blockIdx.y;
  const int d0 = blockIdx.x * 1024 + (threadIdx.x << 2);
  int c = cnt[b];
  if (c > CAP) c = CAP;

  float4 acc = make_float4(0.f, 0.f, 0.f, 0.f);
  for (int j = 0; j < c; ++j) {
    int n = idx[b * CAP + j];
    float w = wv[b * CAP + j];
    float4 im = *(const float4*)&images[(size_t)n * DD + d0];
    acc.x += w * im.x; acc.y += w * im.y;
    acc.z += w * im.z; acc.w += w * im.w;
  }

  const float sval = *svalp;
  const float at = sqrtf(1.f - sval);
  const float inv_bt2 = 1.f / sval;
  float4 xv = *(const float4*)&x[b * DD + d0];
  float4 o;
  o.x = (at * acc.x - xv.x) * inv_bt2;
  o.y = (at * acc.y - xv.y) * inv_bt2;
  o.z = (at * acc.z - xv.z) * inv_bt2;
  o.w = (at * acc.w - xv.w) * inv_bt2;
  *(float4*)&out[b * DD + d0] = o;
}

extern "C" void kernel_launch(void* const* d_in, const int* in_sizes, int n_in,
                              void* d_out, int out_size, void* d_ws, size_t ws_size,
                              hipStream_t stream) {
  const float* x      = (const float*)d_in[0];
  const float* images = (const float*)d_in[1];
  const float* sval   = (const float*)d_in[2];
  float* out = (float*)d_out;
  float* ws  = (float*)d_ws;

  // ws layout (floats): pd[12*16*10000] | cnt[16]i | pad[16] |
  //                     idx[16*1024]i | wv[16*1024]   -> 7.81 MB
  float* pd  = ws;
  int*   cnt = (int*)(ws + 1920000);
  int*   idx = (int*)(ws + 1920032);
  float* wv  = ws + 1936416;

  hipLaunchKernelGGL(k1_partial, dim3(157, QQ), dim3(256), 0, stream,
                     x, images, sval, pd);
  hipLaunchKernelGGL(k2_select, dim3(16), dim3(1024), 0, stream,
                     pd, cnt, idx, wv);
  hipLaunchKernelGGL(k3_sparse, dim3(3, 16), dim3(256), 0, stream,
                     images, x, sval, cnt, idx, wv, out);
}